// Round 1
// baseline (5780.313 us; speedup 1.0000x reference)
//
#include <hip/hip_runtime.h>
#include <hip/hip_bf16.h>
#include <math.h>

// Problem constants (V2TransformerLayer): B=4, T=2048, D=1024, H=16, Dh=64, FF=4096
#define BB   4
#define TT   2048
#define DD   1024
#define HH   16
#define DHH  64
#define FF   4096
#define NTOK (BB*TT)   // 8192

// ---------------------------------------------------------------------------
// LayerNorm: one block per token, 256 threads, 4 floats/thread (float4).
// ---------------------------------------------------------------------------
__global__ __launch_bounds__(256) void ln_kernel(const float* __restrict__ x,
                                                 const float* __restrict__ g,
                                                 const float* __restrict__ be,
                                                 float* __restrict__ y) {
    int tok = blockIdx.x;
    int tid = threadIdx.x;
    const float4* xr = (const float4*)(x + (size_t)tok * DD);
    float4 v = xr[tid];
    float s  = v.x + v.y + v.z + v.w;
    float ss = v.x*v.x + v.y*v.y + v.z*v.z + v.w*v.w;
    #pragma unroll
    for (int m = 32; m >= 1; m >>= 1) {
        s  += __shfl_xor(s,  m);
        ss += __shfl_xor(ss, m);
    }
    __shared__ float red[8];
    int wv = tid >> 6;
    if ((tid & 63) == 0) { red[wv] = s; red[4 + wv] = ss; }
    __syncthreads();
    s  = red[0] + red[1] + red[2] + red[3];
    ss = red[4] + red[5] + red[6] + red[7];
    float mu   = s * (1.0f / DD);
    float var  = ss * (1.0f / DD) - mu * mu;
    float rstd = rsqrtf(var + 1e-5f);
    float4 gv = ((const float4*)g)[tid];
    float4 bv = ((const float4*)be)[tid];
    float4 o;
    o.x = (v.x - mu) * rstd * gv.x + bv.x;
    o.y = (v.y - mu) * rstd * gv.y + bv.y;
    o.z = (v.z - mu) * rstd * gv.z + bv.z;
    o.w = (v.w - mu) * rstd * gv.w + bv.w;
    ((float4*)(y + (size_t)tok * DD))[tid] = o;
}

// ---------------------------------------------------------------------------
// Generic fp32 GEMM:  C[M,N] = A[M,K] @ W[K,N] + bias  (+ epilogue per MODE)
//   MODE 1: scatter to (B,H,T,Dh) layout (QKV projections)
//   MODE 2: plain row-major + residual add
//   MODE 3: plain row-major + exact GELU
// Block tile 64x64, BK=16, 256 threads, 4x4 microtile, LDS pad +4 floats.
// ---------------------------------------------------------------------------
__device__ __forceinline__ float gelu_exact(float x) {
    return 0.5f * x * (1.0f + erff(x * 0.70710678118654752f));
}

template <int MODE>
__global__ __launch_bounds__(256) void gemm_kernel(const float* __restrict__ A,
                                                   const float* __restrict__ W,
                                                   const float* __restrict__ bias,
                                                   float* __restrict__ C,
                                                   int M, int N, int K,
                                                   const float* __restrict__ resid) {
    __shared__ float As[16][68];   // stored transposed: As[k][m]
    __shared__ float Bs[16][68];   // Bs[k][n]
    int tid = threadIdx.x;
    int m0 = blockIdx.y * 64, n0 = blockIdx.x * 64;
    int ty = tid >> 4, tx = tid & 15;      // 16x16 thread grid -> 4x4 micro
    int ar = tid >> 2, ac = tid & 3;       // A-tile load: row ar, float4 col ac
    int br = tid >> 4, bc = tid & 15;      // B-tile load: row br, float4 col bc

    const float* Aptr = A + (size_t)(m0 + ar) * K + ac * 4;
    const float* Wptr = W + (size_t)br * N + n0 + bc * 4;

    float acc[4][4] = {};
    float4 av = *(const float4*)Aptr;
    float4 bv = *(const float4*)Wptr;

    for (int k0 = 0; k0 < K; k0 += 16) {
        As[ac*4+0][ar] = av.x;
        As[ac*4+1][ar] = av.y;
        As[ac*4+2][ar] = av.z;
        As[ac*4+3][ar] = av.w;
        *(float4*)&Bs[br][bc*4] = bv;
        __syncthreads();
        if (k0 + 16 < K) {
            av = *(const float4*)(Aptr + k0 + 16);
            bv = *(const float4*)(Wptr + (size_t)(k0 + 16) * N);
        }
        #pragma unroll
        for (int kk = 0; kk < 16; kk++) {
            float4 a4 = *(const float4*)&As[kk][ty*4];
            float4 b4 = *(const float4*)&Bs[kk][tx*4];
            float a_[4] = {a4.x, a4.y, a4.z, a4.w};
            float b_[4] = {b4.x, b4.y, b4.z, b4.w};
            #pragma unroll
            for (int i = 0; i < 4; i++)
                #pragma unroll
                for (int j = 0; j < 4; j++)
                    acc[i][j] = fmaf(a_[i], b_[j], acc[i][j]);
        }
        __syncthreads();
    }

    float4 bb = *(const float4*)&bias[n0 + tx*4];
    #pragma unroll
    for (int i = 0; i < 4; i++) {
        int row = m0 + ty*4 + i;
        float4 o;
        o.x = acc[i][0] + bb.x;
        o.y = acc[i][1] + bb.y;
        o.z = acc[i][2] + bb.z;
        o.w = acc[i][3] + bb.w;
        if (MODE == 3) {
            o.x = gelu_exact(o.x); o.y = gelu_exact(o.y);
            o.z = gelu_exact(o.z); o.w = gelu_exact(o.w);
        }
        if (MODE == 2) {
            float4 r = *(const float4*)&resid[(size_t)row * N + n0 + tx*4];
            o.x += r.x; o.y += r.y; o.z += r.z; o.w += r.w;
        }
        size_t off;
        if (MODE == 1) {
            int bidx = row >> 11;          // row / T
            int t    = row & 2047;         // row % T
            int h    = n0 >> 6;            // n0 is a multiple of 64
            off = ((size_t)(bidx * HH + h) * TT + t) * DHH + tx*4;
        } else {
            off = (size_t)row * N + n0 + tx*4;
        }
        *(float4*)&C[off] = o;
    }
}

// ---------------------------------------------------------------------------
// Causal flash attention (fp32). One block per (bh, q-tile of 64 rows).
// Q,K,V layout: [(b*H+h)*T + t]*64 + d. K stored transposed in LDS so both
// inner products read contiguous float4 from LDS. Online softmax via 16-lane
// shfl_xor row reductions (rows owned by 16 consecutive lanes).
// ---------------------------------------------------------------------------
__global__ __launch_bounds__(256) void attn_kernel(const float* __restrict__ q,
                                                   const float* __restrict__ k,
                                                   const float* __restrict__ v,
                                                   float* __restrict__ ao) {
    __shared__ float Qs[64][68];
    __shared__ float Kts[64][68];   // Kts[d][kv_row]
    __shared__ float Vs[64][68];
    __shared__ float Ss[64][68];

    int qt  = blockIdx.x;   // 0..31
    int bh  = blockIdx.y;   // 0..63
    int tid = threadIdx.x;
    int ty = tid >> 4, tx = tid & 15;
    const size_t base = (size_t)bh * TT * DHH;
    int qbase = qt * 64;

    // Load Q tile (64x64 floats = 1024 float4, 256 threads -> 4 iters)
    #pragma unroll
    for (int it = 0; it < 4; ++it) {
        int f = it * 256 + tid;
        int row = f >> 4, c4 = f & 15;
        float4 t4 = *(const float4*)&q[base + (size_t)(qbase + row) * DHH + c4*4];
        *(float4*)&Qs[row][c4*4] = t4;
    }

    float m_i[4], l_i[4], o[4][4];
    #pragma unroll
    for (int i = 0; i < 4; i++) {
        m_i[i] = -INFINITY; l_i[i] = 0.0f;
        #pragma unroll
        for (int j = 0; j < 4; j++) o[i][j] = 0.0f;
    }

    for (int kt = 0; kt <= qt; ++kt) {
        int kbase = kt * 64;
        __syncthreads();   // prev-iter LDS reads done (covers Qs writes on iter 0)
        #pragma unroll
        for (int it = 0; it < 4; ++it) {
            int f = it * 256 + tid;
            int row = f >> 4, c4 = f & 15;
            float4 k4 = *(const float4*)&k[base + (size_t)(kbase + row) * DHH + c4*4];
            Kts[c4*4+0][row] = k4.x;
            Kts[c4*4+1][row] = k4.y;
            Kts[c4*4+2][row] = k4.z;
            Kts[c4*4+3][row] = k4.w;
            float4 v4 = *(const float4*)&v[base + (size_t)(kbase + row) * DHH + c4*4];
            *(float4*)&Vs[row][c4*4] = v4;
        }
        __syncthreads();

        // S = Q @ K^T
        float s[4][4] = {};
        #pragma unroll
        for (int k4 = 0; k4 < 16; k4++) {
            float qa[4][4], ka[4][4];
            #pragma unroll
            for (int i = 0; i < 4; i++) {
                float4 t = *(const float4*)&Qs[ty*4 + i][k4*4];
                qa[i][0]=t.x; qa[i][1]=t.y; qa[i][2]=t.z; qa[i][3]=t.w;
            }
            #pragma unroll
            for (int kk = 0; kk < 4; kk++) {
                float4 t = *(const float4*)&Kts[k4*4 + kk][tx*4];
                ka[kk][0]=t.x; ka[kk][1]=t.y; ka[kk][2]=t.z; ka[kk][3]=t.w;
            }
            #pragma unroll
            for (int kk = 0; kk < 4; kk++)
                #pragma unroll
                for (int i = 0; i < 4; i++)
                    #pragma unroll
                    for (int j = 0; j < 4; j++)
                        s[i][j] = fmaf(qa[i][kk], ka[kk][j], s[i][j]);
        }

        // scale + causal mask
        #pragma unroll
        for (int i = 0; i < 4; i++) {
            int gq = qbase + ty*4 + i;
            #pragma unroll
            for (int j = 0; j < 4; j++) {
                int gk = kbase + tx*4 + j;
                s[i][j] = (gk <= gq) ? s[i][j] * 0.125f : -INFINITY;
            }
        }

        // online softmax (row groups = 16 consecutive lanes)
        #pragma unroll
        for (int i = 0; i < 4; i++) {
            float tmax = fmaxf(fmaxf(s[i][0], s[i][1]), fmaxf(s[i][2], s[i][3]));
            #pragma unroll
            for (int mm = 8; mm >= 1; mm >>= 1)
                tmax = fmaxf(tmax, __shfl_xor(tmax, mm));
            float newm  = fmaxf(m_i[i], tmax);
            float alpha = expf(m_i[i] - newm);
            float psum = 0.0f;
            #pragma unroll
            for (int j = 0; j < 4; j++) {
                float p = expf(s[i][j] - newm);
                s[i][j] = p;
                psum += p;
            }
            #pragma unroll
            for (int mm = 8; mm >= 1; mm >>= 1)
                psum += __shfl_xor(psum, mm);
            l_i[i] = l_i[i] * alpha + psum;
            m_i[i] = newm;
            #pragma unroll
            for (int j = 0; j < 4; j++) o[i][j] *= alpha;
            *(float4*)&Ss[ty*4 + i][tx*4] = make_float4(s[i][0], s[i][1], s[i][2], s[i][3]);
        }
        __syncthreads();

        // O += P @ V
        #pragma unroll
        for (int k4 = 0; k4 < 16; k4++) {
            float pa[4][4], va[4][4];
            #pragma unroll
            for (int i = 0; i < 4; i++) {
                float4 t = *(const float4*)&Ss[ty*4 + i][k4*4];
                pa[i][0]=t.x; pa[i][1]=t.y; pa[i][2]=t.z; pa[i][3]=t.w;
            }
            #pragma unroll
            for (int kk = 0; kk < 4; kk++) {
                float4 t = *(const float4*)&Vs[k4*4 + kk][tx*4];
                va[kk][0]=t.x; va[kk][1]=t.y; va[kk][2]=t.z; va[kk][3]=t.w;
            }
            #pragma unroll
            for (int kk = 0; kk < 4; kk++)
                #pragma unroll
                for (int i = 0; i < 4; i++)
                    #pragma unroll
                    for (int j = 0; j < 4; j++)
                        o[i][j] = fmaf(pa[i][kk], va[kk][j], o[i][j]);
        }
    }

    // normalize + write to (B, T, H*Dh)
    int b = bh >> 4, h = bh & 15;
    #pragma unroll
    for (int i = 0; i < 4; i++) {
        float inv = 1.0f / l_i[i];
        int trow = qbase + ty*4 + i;
        float4 oo = make_float4(o[i][0]*inv, o[i][1]*inv, o[i][2]*inv, o[i][3]*inv);
        *(float4*)&ao[((size_t)(b * TT + trow)) * DD + h * DHH + tx*4] = oo;
    }
}

// ---------------------------------------------------------------------------
// Launch. Workspace layout (floats): xn | q | k | v | ao  (5 x 32 MB = 160 MB)
// x2 lives in d_out; FFN hidden h1 reuses q..ao region (128 MB contiguous).
// ---------------------------------------------------------------------------
extern "C" void kernel_launch(void* const* d_in, const int* in_sizes, int n_in,
                              void* d_out, int out_size, void* d_ws, size_t ws_size,
                              hipStream_t stream) {
    const float* x   = (const float*)d_in[0];
    // d_in[1] = attn_mask (causal, hardcoded)
    const float* Wq  = (const float*)d_in[2];
    const float* bq  = (const float*)d_in[3];
    const float* Wk  = (const float*)d_in[4];
    const float* bk  = (const float*)d_in[5];
    const float* Wv  = (const float*)d_in[6];
    const float* bv  = (const float*)d_in[7];
    const float* Wo  = (const float*)d_in[8];
    const float* bo  = (const float*)d_in[9];
    const float* W1  = (const float*)d_in[10];
    const float* b1  = (const float*)d_in[11];
    const float* W2  = (const float*)d_in[12];
    const float* b2  = (const float*)d_in[13];
    const float* g1  = (const float*)d_in[14];
    const float* be1 = (const float*)d_in[15];
    const float* g2  = (const float*)d_in[16];
    const float* be2 = (const float*)d_in[17];

    float* out = (float*)d_out;
    float* ws  = (float*)d_ws;
    const size_t SZ = (size_t)NTOK * DD;   // 8.39M floats = 32 MB

    float* xn = ws;            // LN output (reused for LN2 output)
    float* qb = ws + SZ;
    float* kb = ws + 2 * SZ;
    float* vb = ws + 3 * SZ;
    float* ao = ws + 4 * SZ;
    float* h1 = ws + SZ;       // FFN hidden, reuses qb..ao (128 MB)
    float* x2 = out;           // post-attention residual lives in d_out

    dim3 blk(256);
    dim3 gD(DD / 64, NTOK / 64);     // N=1024 GEMMs: 16 x 128
    dim3 gF(FF / 64, NTOK / 64);     // N=4096 GEMM:  64 x 128

    // 1. LN1
    ln_kernel<<<NTOK, blk, 0, stream>>>(x, g1, be1, xn);
    // 2. Q/K/V projections -> (B,H,T,Dh)
    gemm_kernel<1><<<gD, blk, 0, stream>>>(xn, Wq, bq, qb, NTOK, DD, DD, nullptr);
    gemm_kernel<1><<<gD, blk, 0, stream>>>(xn, Wk, bk, kb, NTOK, DD, DD, nullptr);
    gemm_kernel<1><<<gD, blk, 0, stream>>>(xn, Wv, bv, vb, NTOK, DD, DD, nullptr);
    // 3. causal flash attention -> (B,T,D)
    dim3 gA(TT / 64, BB * HH);
    attn_kernel<<<gA, blk, 0, stream>>>(qb, kb, vb, ao);
    // 4. O projection + residual(x) -> x2 (= d_out)
    gemm_kernel<2><<<gD, blk, 0, stream>>>(ao, Wo, bo, x2, NTOK, DD, DD, x);
    // 5. LN2
    ln_kernel<<<NTOK, blk, 0, stream>>>(x2, g2, be2, xn);
    // 6. FFN up + exact GELU
    gemm_kernel<3><<<gF, blk, 0, stream>>>(xn, W1, b1, h1, NTOK, FF, DD, nullptr);
    // 7. FFN down + residual(x2), in-place safe (read-then-write per element)
    gemm_kernel<2><<<gD, blk, 0, stream>>>(h1, W2, b2, out, NTOK, DD, FF, x2);
}

// Round 7
// 705.944 us; speedup vs baseline: 8.1881x; 8.1881x over previous
//
#include <hip/hip_runtime.h>
#include <hip/hip_bf16.h>
#include <math.h>

// V2TransformerLayer: B=4, T=2048, D=1024, H=16, Dh=64, FF=4096
#define TT   2048
#define DD   1024
#define HHD  16
#define FFD  4096
#define NTOK 8192

typedef __attribute__((ext_vector_type(8))) short bf16x8;
typedef __attribute__((ext_vector_type(4))) float f32x4;
typedef unsigned int u32;
#define AS(n) __attribute__((address_space(n)))

__device__ __forceinline__ unsigned short f2bf(float f) {
    u32 u = __builtin_bit_cast(u32, f);
    u += 0x7fffu + ((u >> 16) & 1u);
    return (unsigned short)(u >> 16);
}

// async global->LDS, 16B per lane. lds ptr must be wave-uniform; g is per-lane.
__device__ __forceinline__ void gld_lds16(const void* g, void* l) {
    __builtin_amdgcn_global_load_lds((const AS(1) u32*)g, (AS(3) u32*)l, 16, 0, 0);
}

// row-dependent 16B-slot swizzle (same function on stage-source and LDS-read)
__device__ __forceinline__ int swz(int row) { return (row + (row >> 3)) & 7; }

// ---------------------------------------------------------------------------
// Weight transpose + cast: W[K][N] fp32 -> Wt[N][K] bf16
// ---------------------------------------------------------------------------
__global__ __launch_bounds__(256) void wtrans(const float* __restrict__ W,
                                              unsigned short* __restrict__ Wt,
                                              int K, int N) {
    __shared__ float t[32][33];
    int tx = threadIdx.x & 31, ty = threadIdx.x >> 5;   // 32 x 8
    int n0 = blockIdx.x * 32, k0 = blockIdx.y * 32;
    #pragma unroll
    for (int i = 0; i < 32; i += 8)
        t[ty + i][tx] = W[(size_t)(k0 + ty + i) * N + n0 + tx];
    __syncthreads();
    #pragma unroll
    for (int i = 0; i < 32; i += 8)
        Wt[(size_t)(n0 + ty + i) * K + k0 + tx] = f2bf(t[tx][ty + i]);
}

// ---------------------------------------------------------------------------
// LayerNorm fp32 in -> bf16 out. One block per token.
// ---------------------------------------------------------------------------
__global__ __launch_bounds__(256) void ln_bf16(const float* __restrict__ x,
                                               const float* __restrict__ g,
                                               const float* __restrict__ be,
                                               unsigned short* __restrict__ y) {
    int tok = blockIdx.x, tid = threadIdx.x;
    float4 v = ((const float4*)(x + (size_t)tok * DD))[tid];
    float s  = v.x + v.y + v.z + v.w;
    float ss = v.x*v.x + v.y*v.y + v.z*v.z + v.w*v.w;
    #pragma unroll
    for (int m = 32; m >= 1; m >>= 1) { s += __shfl_xor(s, m); ss += __shfl_xor(ss, m); }
    __shared__ float red[8];
    if ((tid & 63) == 0) { red[tid >> 6] = s; red[4 + (tid >> 6)] = ss; }
    __syncthreads();
    s  = red[0] + red[1] + red[2] + red[3];
    ss = red[4] + red[5] + red[6] + red[7];
    float mu   = s * (1.0f / DD);
    float rstd = rsqrtf(ss * (1.0f / DD) - mu * mu + 1e-5f);
    float4 gv = ((const float4*)g)[tid];
    float4 bv = ((const float4*)be)[tid];
    ushort4 o;
    o.x = f2bf((v.x - mu) * rstd * gv.x + bv.x);
    o.y = f2bf((v.y - mu) * rstd * gv.y + bv.y);
    o.z = f2bf((v.z - mu) * rstd * gv.z + bv.z);
    o.w = f2bf((v.w - mu) * rstd * gv.w + bv.w);
    *(ushort4*)(y + (size_t)tok * DD + tid * 4) = o;
}

// ---------------------------------------------------------------------------
// bf16 MFMA GEMM: C[M,N] = A[M,K](bf16) @ Bt[N,K](bf16)^T + bias
// 128x128 tile, BK=64, 4 waves (2x2), 4x4 frags of 16x16x32 MFMA.
// MODE 1: scatter bf16 to (B,H,T,Dh); MODE 2: fp32 + resid; MODE 3: GELU bf16
// ---------------------------------------------------------------------------
template <int MODE>
__global__ __launch_bounds__(256, 3) void gemm_bf16(const unsigned short* __restrict__ A,
                                                    const unsigned short* __restrict__ Bt,
                                                    const float* __restrict__ bias,
                                                    void* __restrict__ C,
                                                    const float* __restrict__ resid,
                                                    int M, int N, int K) {
    __shared__ __align__(16) unsigned short As[128 * 64];
    __shared__ __align__(16) unsigned short Bs[128 * 64];
    int tid = threadIdx.x, lane = tid & 63, w = tid >> 6;
    int wm = w >> 1, wn = w & 1;
    int m0 = blockIdx.y * 128, n0 = blockIdx.x * 128;
    int c = lane & 15, g = lane >> 4;

    f32x4 acc[4][4];
    f32x4 z4 = {0.f, 0.f, 0.f, 0.f};
    #pragma unroll
    for (int i = 0; i < 4; ++i)
        #pragma unroll
        for (int j = 0; j < 4; ++j) acc[i][j] = z4;

    // per-lane staging source bases (pre-swizzled k offset)
    const unsigned short* aSrc[4];
    const unsigned short* bSrc[4];
    int ldsOff[4];
    #pragma unroll
    for (int i = 0; i < 4; ++i) {
        int inst = w * 4 + i;
        int row  = inst * 8 + (lane >> 3);
        int kk   = ((lane & 7) ^ swz(row)) << 3;
        aSrc[i] = A  + (size_t)(m0 + row) * K + kk;
        bSrc[i] = Bt + (size_t)(n0 + row) * K + kk;
        ldsOff[i] = inst * 1024;
    }

    for (int k0 = 0; k0 < K; k0 += 64) {
        #pragma unroll
        for (int i = 0; i < 4; ++i) {
            gld_lds16(aSrc[i] + k0, (char*)As + ldsOff[i]);
            gld_lds16(bSrc[i] + k0, (char*)Bs + ldsOff[i]);
        }
        __syncthreads();
        #pragma unroll
        for (int ks = 0; ks < 2; ++ks) {
            bf16x8 af[4], bfr[4];
            int slot = ks * 4 + g;
            #pragma unroll
            for (int f = 0; f < 4; ++f) {
                int ra = wm * 64 + f * 16 + c;
                af[f]  = *(const bf16x8*)((const char*)As + ra * 128 + ((slot ^ swz(ra)) << 4));
                int rb = wn * 64 + f * 16 + c;
                bfr[f] = *(const bf16x8*)((const char*)Bs + rb * 128 + ((slot ^ swz(rb)) << 4));
            }
            #pragma unroll
            for (int i = 0; i < 4; ++i)
                #pragma unroll
                for (int j = 0; j < 4; ++j)
                    acc[i][j] = __builtin_amdgcn_mfma_f32_16x16x32_bf16(af[i], bfr[j], acc[i][j], 0, 0, 0);
        }
        __syncthreads();
    }

    float bcol[4];
    #pragma unroll
    for (int j = 0; j < 4; ++j) bcol[j] = bias[n0 + wn * 64 + j * 16 + c];
    #pragma unroll
    for (int i = 0; i < 4; ++i) {
        #pragma unroll
        for (int r = 0; r < 4; ++r) {
            int rowm = m0 + wm * 64 + i * 16 + g * 4 + r;
            #pragma unroll
            for (int j = 0; j < 4; ++j) {
                float val = acc[i][j][r] + bcol[j];
                int col = n0 + wn * 64 + j * 16 + c;
                if (MODE == 1) {
                    int b = rowm >> 11, t = rowm & 2047, h = col >> 6, d = col & 63;
                    ((unsigned short*)C)[(((size_t)((b << 4) + h) * TT + t) << 6) + d] = f2bf(val);
                } else if (MODE == 2) {
                    size_t idx = (size_t)rowm * N + col;
                    ((float*)C)[idx] = val + resid[idx];
                } else {
                    float ge = 0.5f * val * (1.0f + erff(val * 0.70710678118f));
                    ((unsigned short*)C)[(size_t)rowm * N + col] = f2bf(ge);
                }
            }
        }
    }
}

// ---------------------------------------------------------------------------
// bf16 flash attention, causal. Block = (q-tile of 64 rows, bh). 4 waves,
// wave w owns q rows q0+16w..+15. Q in regs; K,V^T staged in LDS (swizzled);
// P per-wave in LDS. Online softmax in fp32.
// ---------------------------------------------------------------------------
__global__ __launch_bounds__(256) void attn_bf16(const unsigned short* __restrict__ q,
                                                 const unsigned short* __restrict__ k,
                                                 const unsigned short* __restrict__ v,
                                                 unsigned short* __restrict__ ao) {
    __shared__ __align__(16) unsigned short Ks[64 * 64];
    __shared__ __align__(16) unsigned short Vt[64 * 64];
    __shared__ __align__(16) unsigned short Ps[4][16 * 64];
    int tid = threadIdx.x, lane = tid & 63, w = tid >> 6;
    int qt = blockIdx.x, bh = blockIdx.y;
    int q0 = qt * 64;
    size_t base = (size_t)bh * TT * 64;
    int c = lane & 15, g = lane >> 4;

    // Q fragments in registers
    int qrow = q0 + w * 16 + c;
    bf16x8 qf[2];
    qf[0] = *(const bf16x8*)(q + base + (size_t)qrow * 64 + g * 8);
    qf[1] = *(const bf16x8*)(q + base + (size_t)qrow * 64 + 32 + g * 8);

    float m_i[4], l_i[4];
    f32x4 o[4];
    f32x4 z4 = {0.f, 0.f, 0.f, 0.f};
    #pragma unroll
    for (int j = 0; j < 4; ++j) { m_i[j] = -INFINITY; l_i[j] = 0.0f; o[j] = z4; }

    // staging bases
    const unsigned short* kSrc[2];
    int kOff[2];
    #pragma unroll
    for (int i = 0; i < 2; ++i) {
        int inst = w * 2 + i;
        int row  = inst * 8 + (lane >> 3);
        kSrc[i] = k + base + (size_t)row * 64 + (((lane & 7) ^ swz(row)) << 3);
        kOff[i] = inst * 1024;
    }

    for (int kt = 0; kt <= qt; ++kt) {
        int kv0 = kt * 64;
        __syncthreads();   // prev-iter LDS reads done before overwrite
        #pragma unroll
        for (int i = 0; i < 2; ++i)
            gld_lds16(kSrc[i] + (size_t)kv0 * 64, (char*)Ks + kOff[i]);
        // V transposed into Vt[d][kv]
        #pragma unroll
        for (int p = 0; p < 2; ++p) {
            int kvr = w * 16 + p * 8 + (lane >> 3);
            int d0  = (lane & 7) * 8;
            bf16x8 vv = *(const bf16x8*)(v + base + (size_t)(kv0 + kvr) * 64 + d0);
            #pragma unroll
            for (int e = 0; e < 8; ++e) {
                int dr = d0 + e;
                int byte = dr * 128 + ((((kvr >> 3) ^ swz(dr)) << 4)) + ((kvr & 7) << 1);
                *(unsigned short*)((char*)Vt + byte) = (unsigned short)vv[e];
            }
        }
        __syncthreads();

        // S = Q @ K^T  (D row = q-local, col = kv-local)
        f32x4 s[4];
        #pragma unroll
        for (int f = 0; f < 4; ++f) s[f] = z4;
        #pragma unroll
        for (int ks = 0; ks < 2; ++ks) {
            int slot = ks * 4 + g;
            #pragma unroll
            for (int f = 0; f < 4; ++f) {
                int rb = f * 16 + c;
                bf16x8 kf = *(const bf16x8*)((const char*)Ks + rb * 128 + ((slot ^ swz(rb)) << 4));
                s[f] = __builtin_amdgcn_mfma_f32_16x16x32_bf16(qf[ks], kf, s[f], 0, 0, 0);
            }
        }

        bool diag = (kt == qt);
        #pragma unroll
        for (int j = 0; j < 4; ++j) {
            int lq = g * 4 + j;
            int gq = q0 + w * 16 + lq;
            #pragma unroll
            for (int f = 0; f < 4; ++f) {
                float sv = s[f][j] * 0.125f;
                if (diag && (kv0 + f * 16 + c > gq)) sv = -INFINITY;
                s[f][j] = sv;
            }
            float mx = fmaxf(fmaxf(s[0][j], s[1][j]), fmaxf(s[2][j], s[3][j]));
            #pragma unroll
            for (int mm = 8; mm >= 1; mm >>= 1) mx = fmaxf(mx, __shfl_xor(mx, mm));
            float newm = fmaxf(m_i[j], mx);
            float al = __expf(m_i[j] - newm);
            float rs = 0.0f;
            #pragma unroll
            for (int f = 0; f < 4; ++f) {
                float p = __expf(s[f][j] - newm);
                s[f][j] = p;
                rs += p;
            }
            #pragma unroll
            for (int mm = 8; mm >= 1; mm >>= 1) rs += __shfl_xor(rs, mm);
            l_i[j] = l_i[j] * al + rs;
            m_i[j] = newm;
            // write P row (bf16, swizzled) to this wave's region
            #pragma unroll
            for (int f = 0; f < 4; ++f) {
                int col = f * 16 + c;
                int byte = lq * 128 + (((col >> 3) ^ swz(lq)) << 4) + ((col & 7) << 1);
                *(unsigned short*)((char*)Ps[w] + byte) = f2bf(s[f][j]);
            }
            #pragma unroll
            for (int fd = 0; fd < 4; ++fd) o[fd][j] *= al;
        }
        asm volatile("s_waitcnt lgkmcnt(0)" ::: "memory");
        __builtin_amdgcn_sched_barrier(0);   // rule 18: keep PV reads/MFMA below the wait

        // O += P @ V
        #pragma unroll
        for (int ks = 0; ks < 2; ++ks) {
            int slot = ks * 4 + g;
            bf16x8 pa = *(const bf16x8*)((const char*)Ps[w] + c * 128 + ((slot ^ swz(c)) << 4));
            #pragma unroll
            for (int fd = 0; fd < 4; ++fd) {
                int rv = fd * 16 + c;
                bf16x8 vf = *(const bf16x8*)((const char*)Vt + rv * 128 + ((slot ^ swz(rv)) << 4));
                o[fd] = __builtin_amdgcn_mfma_f32_16x16x32_bf16(pa, vf, o[fd], 0, 0, 0);
            }
        }
    }

    int b = bh >> 4, h = bh & 15;
    #pragma unroll
    for (int fd = 0; fd < 4; ++fd)
        #pragma unroll
        for (int j = 0; j < 4; ++j) {
            int t = q0 + w * 16 + g * 4 + j;
            float val = o[fd][j] / l_i[j];
            ao[(((size_t)(b * TT + t)) << 10) + (h << 6) + fd * 16 + c] = f2bf(val);
        }
}

// ---------------------------------------------------------------------------
// Launch. ws (bytes): [0,16M) xn | [16,32M) q | [32,48M) k | [48,64M) v |
// [64,80M) ao | [80,104M) Wt's.  h1 (64MB) reuses q..ao. x2 = d_out (fp32).
// ---------------------------------------------------------------------------
extern "C" void kernel_launch(void* const* d_in, const int* in_sizes, int n_in,
                              void* d_out, int out_size, void* d_ws, size_t ws_size,
                              hipStream_t stream) {
    const float* x   = (const float*)d_in[0];
    const float* Wq  = (const float*)d_in[2];
    const float* bq  = (const float*)d_in[3];
    const float* Wk  = (const float*)d_in[4];
    const float* bk  = (const float*)d_in[5];
    const float* Wv  = (const float*)d_in[6];
    const float* bv  = (const float*)d_in[7];
    const float* Wo  = (const float*)d_in[8];
    const float* bo  = (const float*)d_in[9];
    const float* W1  = (const float*)d_in[10];
    const float* b1  = (const float*)d_in[11];
    const float* W2  = (const float*)d_in[12];
    const float* b2  = (const float*)d_in[13];
    const float* g1  = (const float*)d_in[14];
    const float* be1 = (const float*)d_in[15];
    const float* g2  = (const float*)d_in[16];
    const float* be2 = (const float*)d_in[17];

    float* out = (float*)d_out;
    char* w = (char*)d_ws;
    const size_t MB = 1024 * 1024;
    unsigned short* xnb = (unsigned short*)(w);
    unsigned short* qb  = (unsigned short*)(w + 16 * MB);
    unsigned short* kb  = (unsigned short*)(w + 32 * MB);
    unsigned short* vb  = (unsigned short*)(w + 48 * MB);
    unsigned short* aob = (unsigned short*)(w + 64 * MB);
    unsigned short* wqt = (unsigned short*)(w + 80 * MB);
    unsigned short* wkt = wqt + 1 * MB;     // element (2B) offsets: 2MB each
    unsigned short* wvt = wqt + 2 * MB;
    unsigned short* wot = wqt + 3 * MB;
    unsigned short* w1t = wqt + 4 * MB;     // 8MB
    unsigned short* w2t = w1t + 4 * MB;     // 8MB
    unsigned short* h1  = qb;               // 64MB, reuses q/k/v/ao

    dim3 blk(256);
    wtrans<<<dim3(DD / 32, DD / 32), blk, 0, stream>>>(Wq, wqt, DD, DD);
    wtrans<<<dim3(DD / 32, DD / 32), blk, 0, stream>>>(Wk, wkt, DD, DD);
    wtrans<<<dim3(DD / 32, DD / 32), blk, 0, stream>>>(Wv, wvt, DD, DD);
    wtrans<<<dim3(DD / 32, DD / 32), blk, 0, stream>>>(Wo, wot, DD, DD);
    wtrans<<<dim3(FFD / 32, DD / 32), blk, 0, stream>>>(W1, w1t, DD, FFD);
    wtrans<<<dim3(DD / 32, FFD / 32), blk, 0, stream>>>(W2, w2t, FFD, DD);

    ln_bf16<<<NTOK, blk, 0, stream>>>(x, g1, be1, xnb);

    dim3 gD(DD / 128, NTOK / 128);    // (8, 64)
    dim3 gF(FFD / 128, NTOK / 128);   // (32, 64)
    gemm_bf16<1><<<gD, blk, 0, stream>>>(xnb, wqt, bq, qb, nullptr, NTOK, DD, DD);
    gemm_bf16<1><<<gD, blk, 0, stream>>>(xnb, wkt, bk, kb, nullptr, NTOK, DD, DD);
    gemm_bf16<1><<<gD, blk, 0, stream>>>(xnb, wvt, bv, vb, nullptr, NTOK, DD, DD);

    attn_bf16<<<dim3(TT / 64, 64), blk, 0, stream>>>(qb, kb, vb, aob);

    gemm_bf16<2><<<gD, blk, 0, stream>>>(aob, wot, bo, out, x, NTOK, DD, DD);
    ln_bf16<<<NTOK, blk, 0, stream>>>(out, g2, be2, xnb);
    gemm_bf16<3><<<gF, blk, 0, stream>>>(xnb, w1t, b1, h1, nullptr, NTOK, FFD, DD);
    gemm_bf16<2><<<gD, blk, 0, stream>>>(h1, w2t, b2, out, out, NTOK, DD, FFD);
}

// Round 11
// 586.415 us; speedup vs baseline: 9.8570x; 1.2038x over previous
//
#include <hip/hip_runtime.h>
#include <hip/hip_bf16.h>
#include <math.h>

// V2TransformerLayer: B=4, T=2048, D=1024, H=16, Dh=64, FF=4096
#define TT   2048
#define DD   1024
#define HHD  16
#define FFD  4096
#define NTOK 8192

typedef __attribute__((ext_vector_type(8))) short bf16x8;
typedef __attribute__((ext_vector_type(4))) float f32x4;
typedef unsigned int u32;
#define AS(n) __attribute__((address_space(n)))

__device__ __forceinline__ unsigned short f2bf(float f) {
    u32 u = __builtin_bit_cast(u32, f);
    u += 0x7fffu + ((u >> 16) & 1u);
    return (unsigned short)(u >> 16);
}

// async global->LDS, 16B per lane. lds ptr must be wave-uniform; g is per-lane.
__device__ __forceinline__ void gld_lds16(const void* g, void* l) {
    __builtin_amdgcn_global_load_lds((const AS(1) u32*)g, (AS(3) u32*)l, 16, 0, 0);
}

// row-dependent 16B-slot swizzle (same function on stage-source and LDS-read)
__device__ __forceinline__ int swz(int row) { return (row + (row >> 3)) & 7; }

// ---------------------------------------------------------------------------
// Weight transpose + cast: W[K][N] fp32 -> Wt[N][K] bf16
// ---------------------------------------------------------------------------
__global__ __launch_bounds__(256) void wtrans(const float* __restrict__ W,
                                              unsigned short* __restrict__ Wt,
                                              int K, int N) {
    __shared__ float t[32][33];
    int tx = threadIdx.x & 31, ty = threadIdx.x >> 5;   // 32 x 8
    int n0 = blockIdx.x * 32, k0 = blockIdx.y * 32;
    #pragma unroll
    for (int i = 0; i < 32; i += 8)
        t[ty + i][tx] = W[(size_t)(k0 + ty + i) * N + n0 + tx];
    __syncthreads();
    #pragma unroll
    for (int i = 0; i < 32; i += 8)
        Wt[(size_t)(n0 + ty + i) * K + k0 + tx] = f2bf(t[tx][ty + i]);
}

// ---------------------------------------------------------------------------
// LayerNorm fp32 in -> bf16 out. One block per token.
// ---------------------------------------------------------------------------
__global__ __launch_bounds__(256) void ln_bf16(const float* __restrict__ x,
                                               const float* __restrict__ g,
                                               const float* __restrict__ be,
                                               unsigned short* __restrict__ y) {
    int tok = blockIdx.x, tid = threadIdx.x;
    float4 v = ((const float4*)(x + (size_t)tok * DD))[tid];
    float s  = v.x + v.y + v.z + v.w;
    float ss = v.x*v.x + v.y*v.y + v.z*v.z + v.w*v.w;
    #pragma unroll
    for (int m = 32; m >= 1; m >>= 1) { s += __shfl_xor(s, m); ss += __shfl_xor(ss, m); }
    __shared__ float red[8];
    if ((tid & 63) == 0) { red[tid >> 6] = s; red[4 + (tid >> 6)] = ss; }
    __syncthreads();
    s  = red[0] + red[1] + red[2] + red[3];
    ss = red[4] + red[5] + red[6] + red[7];
    float mu   = s * (1.0f / DD);
    float rstd = rsqrtf(ss * (1.0f / DD) - mu * mu + 1e-5f);
    float4 gv = ((const float4*)g)[tid];
    float4 bv = ((const float4*)be)[tid];
    ushort4 o;
    o.x = f2bf((v.x - mu) * rstd * gv.x + bv.x);
    o.y = f2bf((v.y - mu) * rstd * gv.y + bv.y);
    o.z = f2bf((v.z - mu) * rstd * gv.z + bv.z);
    o.w = f2bf((v.w - mu) * rstd * gv.w + bv.w);
    *(ushort4*)(y + (size_t)tok * DD + tid * 4) = o;
}

// ---------------------------------------------------------------------------
// bf16 MFMA GEMM: C[M,N] = A[M,K](bf16) @ Bt[N,K](bf16)^T + bias
// 128x128 tile, BK=64, 4 waves (2x2), 4x4 frags of 16x16x32 MFMA.
// MODE 1: scatter bf16 to (B,H,T,Dh)     (bias per col)
// MODE 2: fp32 + resid                   (bias per col)
// MODE 3: GELU bf16                      (bias per col)
// MODE 4: scatter bf16 to (B,H,Dh,T)  — for A=W^T, Bt=x: C=(x@W)^T  (bias per ROW)
// ---------------------------------------------------------------------------
template <int MODE>
__global__ __launch_bounds__(256, 3) void gemm_bf16(const unsigned short* __restrict__ A,
                                                    const unsigned short* __restrict__ Bt,
                                                    const float* __restrict__ bias,
                                                    void* __restrict__ C,
                                                    const float* __restrict__ resid,
                                                    int M, int N, int K) {
    __shared__ __align__(16) unsigned short As[128 * 64];
    __shared__ __align__(16) unsigned short Bs[128 * 64];
    int tid = threadIdx.x, lane = tid & 63, w = tid >> 6;
    int wm = w >> 1, wn = w & 1;
    int m0 = blockIdx.y * 128, n0 = blockIdx.x * 128;
    int c = lane & 15, g = lane >> 4;

    f32x4 acc[4][4];
    f32x4 z4 = {0.f, 0.f, 0.f, 0.f};
    #pragma unroll
    for (int i = 0; i < 4; ++i)
        #pragma unroll
        for (int j = 0; j < 4; ++j) acc[i][j] = z4;

    // per-lane staging source bases (pre-swizzled k offset)
    const unsigned short* aSrc[4];
    const unsigned short* bSrc[4];
    int ldsOff[4];
    #pragma unroll
    for (int i = 0; i < 4; ++i) {
        int inst = w * 4 + i;
        int row  = inst * 8 + (lane >> 3);
        int kk   = ((lane & 7) ^ swz(row)) << 3;
        aSrc[i] = A  + (size_t)(m0 + row) * K + kk;
        bSrc[i] = Bt + (size_t)(n0 + row) * K + kk;
        ldsOff[i] = inst * 1024;
    }

    for (int k0 = 0; k0 < K; k0 += 64) {
        #pragma unroll
        for (int i = 0; i < 4; ++i) {
            gld_lds16(aSrc[i] + k0, (char*)As + ldsOff[i]);
            gld_lds16(bSrc[i] + k0, (char*)Bs + ldsOff[i]);
        }
        __syncthreads();
        #pragma unroll
        for (int ks = 0; ks < 2; ++ks) {
            bf16x8 af[4], bfr[4];
            int slot = ks * 4 + g;
            #pragma unroll
            for (int f = 0; f < 4; ++f) {
                int ra = wm * 64 + f * 16 + c;
                af[f]  = *(const bf16x8*)((const char*)As + ra * 128 + ((slot ^ swz(ra)) << 4));
                int rb = wn * 64 + f * 16 + c;
                bfr[f] = *(const bf16x8*)((const char*)Bs + rb * 128 + ((slot ^ swz(rb)) << 4));
            }
            #pragma unroll
            for (int i = 0; i < 4; ++i)
                #pragma unroll
                for (int j = 0; j < 4; ++j)
                    acc[i][j] = __builtin_amdgcn_mfma_f32_16x16x32_bf16(af[i], bfr[j], acc[i][j], 0, 0, 0);
        }
        __syncthreads();
    }

    float bcol[4];
    float4 brow[4];
    if (MODE == 4) {
        #pragma unroll
        for (int i = 0; i < 4; ++i)
            brow[i] = *(const float4*)&bias[m0 + wm * 64 + i * 16 + g * 4];
    } else {
        #pragma unroll
        for (int j = 0; j < 4; ++j) bcol[j] = bias[n0 + wn * 64 + j * 16 + c];
    }
    #pragma unroll
    for (int i = 0; i < 4; ++i) {
        #pragma unroll
        for (int r = 0; r < 4; ++r) {
            int rowm = m0 + wm * 64 + i * 16 + g * 4 + r;
            float br = (MODE == 4) ? ((const float*)&brow[i])[r] : 0.0f;
            #pragma unroll
            for (int j = 0; j < 4; ++j) {
                float val = acc[i][j][r] + ((MODE == 4) ? br : bcol[j]);
                int col = n0 + wn * 64 + j * 16 + c;
                if (MODE == 1) {
                    int b = rowm >> 11, t = rowm & 2047, h = col >> 6, d = col & 63;
                    ((unsigned short*)C)[(((size_t)((b << 4) + h) * TT + t) << 6) + d] = f2bf(val);
                } else if (MODE == 2) {
                    size_t idx = (size_t)rowm * N + col;
                    ((float*)C)[idx] = val + resid[idx];
                } else if (MODE == 3) {
                    float ge = 0.5f * val * (1.0f + erff(val * 0.70710678118f));
                    ((unsigned short*)C)[(size_t)rowm * N + col] = f2bf(ge);
                } else {
                    // MODE 4: rowm = out-dim, col = token  ->  [bh][d][t]
                    int b = col >> 11, t = col & 2047, h = rowm >> 6, d = rowm & 63;
                    ((unsigned short*)C)[(((size_t)((b << 4) + h) * 64 + d) << 11) + t] = f2bf(val);
                }
            }
        }
    }
}

// ---------------------------------------------------------------------------
// bf16 flash attention, causal. Pair-balanced: block handles q-tiles {p,31-p}
// (uniform 33 kv-tile iterations). Grid = 1024 blocks = 4/CU, all resident.
// XCD decode clusters all 16 blocks of one bh on one XCD (K/V L2 reuse).
// K [bh][t][d] and V^T [bh][d][t] double-buffered in LDS via global_load_lds
// (swizzled); Q in regs; P per-wave in LDS. One barrier per tile; staging of
// tile t+1 overlaps compute of tile t. setprio(1) around MFMA clusters (T5).
// ---------------------------------------------------------------------------
__global__ __launch_bounds__(256, 4) void attn_bf16(const unsigned short* __restrict__ q,
                                                    const unsigned short* __restrict__ k,
                                                    const unsigned short* __restrict__ vt,
                                                    unsigned short* __restrict__ ao) {
    __shared__ __align__(16) unsigned short Ks[2][64 * 64];
    __shared__ __align__(16) unsigned short Vts[2][64 * 64];
    __shared__ __align__(16) unsigned short Ps[4][16 * 64];
    int tid = threadIdx.x, lane = tid & 63, w = tid >> 6;
    int bid = blockIdx.x;                       // 0..1023
    int bh  = (bid & 7) * 8 + ((bid >> 3) & 7); // XCD-clustered bh
    int pr  = bid >> 6;                         // pair index 0..15
    int c = lane & 15, g = lane >> 4;
    size_t kbase = (size_t)bh * TT * 64;        // Q,K: [bh][t][64]
    size_t vbase = (size_t)bh * 64 * TT;        // V^T: [bh][64][t]

    // staging descriptors (2 gld_lds16 per wave per tensor)
    const unsigned short* kSrc[2];
    const unsigned short* vSrc[2];
    int ldsOff[2];
    #pragma unroll
    for (int i = 0; i < 2; ++i) {
        int inst = w * 2 + i;
        int row  = inst * 8 + (lane >> 3);
        int kk   = ((lane & 7) ^ swz(row)) << 3;
        kSrc[i] = k  + kbase + (size_t)row * 64 + kk;
        vSrc[i] = vt + vbase + (size_t)row * TT + kk;
        ldsOff[i] = inst * 1024;
    }

    auto STAGE = [&](int buf, int kv0) {
        #pragma unroll
        for (int i = 0; i < 2; ++i) {
            gld_lds16(kSrc[i] + (size_t)kv0 * 64, (char*)Ks[buf] + ldsOff[i]);
            gld_lds16(vSrc[i] + kv0,              (char*)Vts[buf] + ldsOff[i]);
        }
    };

    int b = bh >> 4, h = bh & 15;
    f32x4 z4 = {0.f, 0.f, 0.f, 0.f};

    for (int ph = 0; ph < 2; ++ph) {
        int qt = ph ? (31 - pr) : pr;
        int q0 = qt * 64;
        int qrow = q0 + w * 16 + c;
        bf16x8 qf[2];
        qf[0] = *(const bf16x8*)(q + kbase + (size_t)qrow * 64 + g * 8);
        qf[1] = *(const bf16x8*)(q + kbase + (size_t)qrow * 64 + 32 + g * 8);

        float m_i[4], l_i[4];
        f32x4 o[4];
        #pragma unroll
        for (int j = 0; j < 4; ++j) { m_i[j] = -INFINITY; l_i[j] = 0.0f; o[j] = z4; }

        __syncthreads();            // all waves done reading prev phase's LDS
        STAGE(0, 0);

        for (int kt = 0; kt <= qt; ++kt) {
            int cur = kt & 1, kv0 = kt * 64;
            __syncthreads();        // buf cur staged (vmcnt drained); buf cur^1 free
            if (kt < qt) STAGE(cur ^ 1, kv0 + 64);

            // S = Q @ K^T
            f32x4 s[4];
            #pragma unroll
            for (int f = 0; f < 4; ++f) s[f] = z4;
            __builtin_amdgcn_s_setprio(1);
            #pragma unroll
            for (int ks = 0; ks < 2; ++ks) {
                int slot = ks * 4 + g;
                #pragma unroll
                for (int f = 0; f < 4; ++f) {
                    int rb = f * 16 + c;
                    bf16x8 kf = *(const bf16x8*)((const char*)Ks[cur] + rb * 128 + ((slot ^ swz(rb)) << 4));
                    s[f] = __builtin_amdgcn_mfma_f32_16x16x32_bf16(qf[ks], kf, s[f], 0, 0, 0);
                }
            }
            __builtin_amdgcn_s_setprio(0);

            bool diag = (kt == qt);
            #pragma unroll
            for (int j = 0; j < 4; ++j) {
                int lq = g * 4 + j;
                int gq = q0 + w * 16 + lq;
                #pragma unroll
                for (int f = 0; f < 4; ++f) {
                    float sv = s[f][j] * 0.125f;
                    if (diag && (kv0 + f * 16 + c > gq)) sv = -INFINITY;
                    s[f][j] = sv;
                }
                float mx = fmaxf(fmaxf(s[0][j], s[1][j]), fmaxf(s[2][j], s[3][j]));
                #pragma unroll
                for (int mm = 8; mm >= 1; mm >>= 1) mx = fmaxf(mx, __shfl_xor(mx, mm));
                float newm = fmaxf(m_i[j], mx);
                float al = __expf(m_i[j] - newm);
                float rs = 0.0f;
                #pragma unroll
                for (int f = 0; f < 4; ++f) {
                    float p = __expf(s[f][j] - newm);
                    s[f][j] = p;
                    rs += p;
                }
                #pragma unroll
                for (int mm = 8; mm >= 1; mm >>= 1) rs += __shfl_xor(rs, mm);
                l_i[j] = l_i[j] * al + rs;
                m_i[j] = newm;
                #pragma unroll
                for (int f = 0; f < 4; ++f) {
                    int col = f * 16 + c;
                    int byte = lq * 128 + (((col >> 3) ^ swz(lq)) << 4) + ((col & 7) << 1);
                    *(unsigned short*)((char*)Ps[w] + byte) = f2bf(s[f][j]);
                }
                #pragma unroll
                for (int fd = 0; fd < 4; ++fd) o[fd][j] *= al;
            }
            asm volatile("s_waitcnt lgkmcnt(0)" ::: "memory");
            __builtin_amdgcn_sched_barrier(0);   // rule 18: keep PV below the wait

            // O += P @ V
            __builtin_amdgcn_s_setprio(1);
            #pragma unroll
            for (int ks = 0; ks < 2; ++ks) {
                int slot = ks * 4 + g;
                bf16x8 pa = *(const bf16x8*)((const char*)Ps[w] + c * 128 + ((slot ^ swz(c)) << 4));
                #pragma unroll
                for (int fd = 0; fd < 4; ++fd) {
                    int rv = fd * 16 + c;
                    bf16x8 vf = *(const bf16x8*)((const char*)Vts[cur] + rv * 128 + ((slot ^ swz(rv)) << 4));
                    o[fd] = __builtin_amdgcn_mfma_f32_16x16x32_bf16(pa, vf, o[fd], 0, 0, 0);
                }
            }
            __builtin_amdgcn_s_setprio(0);
        }

        #pragma unroll
        for (int fd = 0; fd < 4; ++fd)
            #pragma unroll
            for (int j = 0; j < 4; ++j) {
                int t = q0 + w * 16 + g * 4 + j;
                float val = o[fd][j] / l_i[j];
                ao[(((size_t)(b * TT + t)) << 10) + (h << 6) + fd * 16 + c] = f2bf(val);
            }
    }
}

// ---------------------------------------------------------------------------
// Launch. ws (bytes): [0,16M) xn | [16,32M) q | [32,48M) k | [48,64M) v^T |
// [64,80M) ao | [80,104M) Wt's.  h1 (64MB) reuses q..ao. x2 = d_out (fp32).
// ---------------------------------------------------------------------------
extern "C" void kernel_launch(void* const* d_in, const int* in_sizes, int n_in,
                              void* d_out, int out_size, void* d_ws, size_t ws_size,
                              hipStream_t stream) {
    const float* x   = (const float*)d_in[0];
    const float* Wq  = (const float*)d_in[2];
    const float* bq  = (const float*)d_in[3];
    const float* Wk  = (const float*)d_in[4];
    const float* bk  = (const float*)d_in[5];
    const float* Wv  = (const float*)d_in[6];
    const float* bv  = (const float*)d_in[7];
    const float* Wo  = (const float*)d_in[8];
    const float* bo  = (const float*)d_in[9];
    const float* W1  = (const float*)d_in[10];
    const float* b1  = (const float*)d_in[11];
    const float* W2  = (const float*)d_in[12];
    const float* b2  = (const float*)d_in[13];
    const float* g1  = (const float*)d_in[14];
    const float* be1 = (const float*)d_in[15];
    const float* g2  = (const float*)d_in[16];
    const float* be2 = (const float*)d_in[17];

    float* out = (float*)d_out;
    char* w = (char*)d_ws;
    const size_t MB = 1024 * 1024;
    unsigned short* xnb = (unsigned short*)(w);
    unsigned short* qb  = (unsigned short*)(w + 16 * MB);
    unsigned short* kb  = (unsigned short*)(w + 32 * MB);
    unsigned short* vb  = (unsigned short*)(w + 48 * MB);   // holds V^T [bh][d][t]
    unsigned short* aob = (unsigned short*)(w + 64 * MB);
    unsigned short* wqt = (unsigned short*)(w + 80 * MB);
    unsigned short* wkt = wqt + 1 * MB;     // element (2B) offsets: 2MB each
    unsigned short* wvt = wqt + 2 * MB;
    unsigned short* wot = wqt + 3 * MB;
    unsigned short* w1t = wqt + 4 * MB;     // 8MB
    unsigned short* w2t = w1t + 4 * MB;     // 8MB
    unsigned short* h1  = qb;               // 64MB, reuses q/k/v/ao

    dim3 blk(256);
    wtrans<<<dim3(DD / 32, DD / 32), blk, 0, stream>>>(Wq, wqt, DD, DD);
    wtrans<<<dim3(DD / 32, DD / 32), blk, 0, stream>>>(Wk, wkt, DD, DD);
    wtrans<<<dim3(DD / 32, DD / 32), blk, 0, stream>>>(Wv, wvt, DD, DD);
    wtrans<<<dim3(DD / 32, DD / 32), blk, 0, stream>>>(Wo, wot, DD, DD);
    wtrans<<<dim3(FFD / 32, DD / 32), blk, 0, stream>>>(W1, w1t, DD, FFD);
    wtrans<<<dim3(DD / 32, FFD / 32), blk, 0, stream>>>(W2, w2t, FFD, DD);

    ln_bf16<<<NTOK, blk, 0, stream>>>(x, g1, be1, xnb);

    dim3 gD(DD / 128, NTOK / 128);    // (8, 64)
    dim3 gF(FFD / 128, NTOK / 128);   // (32, 64)
    dim3 gV(NTOK / 128, DD / 128);    // (64, 8)  — transposed-V GEMM
    gemm_bf16<1><<<gD, blk, 0, stream>>>(xnb, wqt, bq, qb, nullptr, NTOK, DD, DD);
    gemm_bf16<1><<<gD, blk, 0, stream>>>(xnb, wkt, bk, kb, nullptr, NTOK, DD, DD);
    // V^T = Wv^T @ xn^T : A = wvt [1024][1024], Bt = xnb [8192][1024]
    gemm_bf16<4><<<gV, blk, 0, stream>>>(wvt, xnb, bv, vb, nullptr, DD, NTOK, DD);

    attn_bf16<<<dim3(1024), blk, 0, stream>>>(qb, kb, vb, aob);

    gemm_bf16<2><<<gD, blk, 0, stream>>>(aob, wot, bo, out, x, NTOK, DD, DD);
    ln_bf16<<<NTOK, blk, 0, stream>>>(out, g2, be2, xnb);
    gemm_bf16<3><<<gF, blk, 0, stream>>>(xnb, w1t, b1, h1, nullptr, NTOK, FFD, DD);
    gemm_bf16<2><<<gD, blk, 0, stream>>>(h1, w2t, b2, out, out, NTOK, DD, FFD);
}